// Round 6
// baseline (69.649 us; speedup 1.0000x reference)
//
#include <hip/hip_runtime.h>

// CapsuleLayer dynamic routing, fused, coalesced, W shared across 2 batches,
// register-double-buffered W prefetch (round-6: attack L2 latency exposure).
// x: [B=256, R=1152, I=8] f32; W: [C=10, R=1152, I=8, O=16] f32
// out: v = [B, C, 1, 1, O=16] f32
//
// One block per (c, b-pair). 512 threads; quad of lanes owns one route node
// (oq = tid&3 owns outputs [4*oq,4*oq+4)). Each W float4 feeds FMAs for BOTH
// batches. Batch 0's u in registers, batch 1's u in LDS private scratch
// (own slots only -> no sync; 0.03% bank conflict measured, irrelevant).
// u-compute k-loop is software-pipelined: pass k+1's 8 W-loads issue before
// pass k's FMAs, so ~250cy L2 latency hides under ~260cy of FMA work.
// Fully unrolled so wb[k&1] indices are compile-time (no scratch, rule #20).
// VGPR budget: u0 36 + logits 18 + 2x8 float4 W bufs 64 -> ~116 < 128 cap
// from __launch_bounds__(512,2).

#define B_ 256
#define C_ 10
#define R_ 1152
#define I_ 8
#define O_ 16
#define T_ 512
#define BPB 2            // batches per block
#define RPP 128          // r's per pass = T_/4
#define KPT 9            // passes = R_/RPP
#define NW 8             // waves per block
#define NITER 3

__global__ __launch_bounds__(T_, 2) void capsule_routing_kernel(
    const float* __restrict__ x,   // [B, R, I]
    const float* __restrict__ w,   // [C, R, I, O]
    float* __restrict__ out)       // [B, C, O]
{
    const int c    = blockIdx.x >> 7;     // c-major: 128 b-pairs per c
    const int bh   = blockIdx.x & 127;
    const int b0   = bh * BPB;
    const int tid  = threadIdx.x;
    const int lane = tid & 63;
    const int wid  = tid >> 6;
    const int oq   = tid & 3;      // which o-quad this lane owns
    const int rl   = tid >> 2;     // route-node slot within pass [0,128)

    __shared__ float u1s[R_][O_];          // 72 KB: batch (b0+1)'s u, private scratch
    __shared__ float sred[BPB][NW][4][4];  // per-wave partial s, by o-quad
    __shared__ float zred[BPB][NW];        // per-wave partial Z
    __shared__ float vfin[BPB][O_];        // final v per iteration

    float u0[KPT][4];      // batch b0's u: registers
    float lg0[KPT], lg1[KPT];

    // ---- u-compute with W register double-buffer ----
    const float* wbase = w + (size_t)c * R_ * (I_ * O_) + oq * 4;
    float4 wb[2][I_];      // two 8xfloat4 buffers (indices always compile-time)

    // prologue: issue pass 0's W loads
    {
        const float* wp = wbase + (size_t)rl * (I_ * O_);
        #pragma unroll
        for (int i = 0; i < I_; ++i) wb[0][i] = *(const float4*)(wp + i * O_);
    }

    #pragma unroll
    for (int k = 0; k < KPT; ++k) {
        // issue pass k+1's W loads into the alternate buffer (overlaps k's FMAs)
        if (k + 1 < KPT) {
            const float* wp = wbase + (size_t)((k + 1) * RPP + rl) * (I_ * O_);
            #pragma unroll
            for (int i = 0; i < I_; ++i) wb[(k + 1) & 1][i] = *(const float4*)(wp + i * O_);
        }

        const int r = k * RPP + rl;
        const float4* xp0 = (const float4*)(x + ((size_t)b0 * R_ + r) * I_);
        const float4 xa0 = xp0[0];
        const float4 xb0 = xp0[1];
        const float4* xp1 = (const float4*)(x + ((size_t)(b0 + 1) * R_ + r) * I_);
        const float4 xa1 = xp1[0];
        const float4 xb1 = xp1[1];
        const float xs0[8] = {xa0.x, xa0.y, xa0.z, xa0.w, xb0.x, xb0.y, xb0.z, xb0.w};
        const float xs1[8] = {xa1.x, xa1.y, xa1.z, xa1.w, xb1.x, xb1.y, xb1.z, xb1.w};

        float4 a0 = make_float4(0.f, 0.f, 0.f, 0.f);
        float4 a1 = make_float4(0.f, 0.f, 0.f, 0.f);
        #pragma unroll
        for (int i = 0; i < I_; ++i) {
            const float4 wv = wb[k & 1][i];
            a0.x += xs0[i] * wv.x;  a1.x += xs1[i] * wv.x;
            a0.y += xs0[i] * wv.y;  a1.y += xs1[i] * wv.y;
            a0.z += xs0[i] * wv.z;  a1.z += xs1[i] * wv.z;
            a0.w += xs0[i] * wv.w;  a1.w += xs1[i] * wv.w;
        }
        u0[k][0] = a0.x; u0[k][1] = a0.y; u0[k][2] = a0.z; u0[k][3] = a0.w;
        *(float4*)&u1s[r][oq * 4] = a1;   // own slot only; no sync needed
        lg0[k] = 0.f;
        lg1[k] = 0.f;
    }

    // ---- routing iterations ----
    for (int it = 0; it < NITER; ++it) {
        // 1) per-thread partial {Z, s} for both b's
        float z0 = 0.f, z1 = 0.f;
        float s00 = 0.f, s01 = 0.f, s02 = 0.f, s03 = 0.f;
        float s10 = 0.f, s11 = 0.f, s12 = 0.f, s13 = 0.f;
        #pragma unroll
        for (int k = 0; k < KPT; ++k) {
            const float e0 = __expf(lg0[k]);
            z0 += e0;
            s00 += e0 * u0[k][0]; s01 += e0 * u0[k][1];
            s02 += e0 * u0[k][2]; s03 += e0 * u0[k][3];
            const int r = k * RPP + rl;
            const float4 uv = *(const float4*)&u1s[r][oq * 4];
            const float e1 = __expf(lg1[k]);
            z1 += e1;
            s10 += e1 * uv.x; s11 += e1 * uv.y;
            s12 += e1 * uv.z; s13 += e1 * uv.w;
        }
        // wave butterfly over the 16 quads (oq kept separate)
        #pragma unroll
        for (int off = 4; off <= 32; off <<= 1) {
            z0 += __shfl_xor(z0, off);   z1 += __shfl_xor(z1, off);
            s00 += __shfl_xor(s00, off); s01 += __shfl_xor(s01, off);
            s02 += __shfl_xor(s02, off); s03 += __shfl_xor(s03, off);
            s10 += __shfl_xor(s10, off); s11 += __shfl_xor(s11, off);
            s12 += __shfl_xor(s12, off); s13 += __shfl_xor(s13, off);
        }
        if (lane < 4) {   // lane == oq here
            sred[0][wid][lane][0] = s00; sred[0][wid][lane][1] = s01;
            sred[0][wid][lane][2] = s02; sred[0][wid][lane][3] = s03;
            sred[1][wid][lane][0] = s10; sred[1][wid][lane][1] = s11;
            sred[1][wid][lane][2] = s12; sred[1][wid][lane][3] = s13;
            if (lane == 0) { zred[0][wid] = z0; zred[1][wid] = z1; }
        }
        __syncthreads();

        // 2) wave 0 finalizes both b's: lanes 0-15 -> b0, lanes 16-31 -> b0+1
        if (wid == 0 && lane < 2 * O_) {
            const int bb = lane >> 4;
            const int o  = lane & 15;
            float S = 0.f, Z = 0.f;
            #pragma unroll
            for (int wv = 0; wv < NW; ++wv) {
                S += sred[bb][wv][o >> 2][o & 3];
                Z += zred[bb][wv];
            }
            float p = S * S;   // butterfly within the 16-lane group -> |s|^2
            p += __shfl_xor(p, 1);
            p += __shfl_xor(p, 2);
            p += __shfl_xor(p, 4);
            p += __shfl_xor(p, 8);
            const float inv = 1.f / Z;
            const float svn = S * inv;
            const float sqn = p * inv * inv;
            const float scale = sqrtf(sqn) / (1.f + sqn);
            const float vf = svn * scale;
            vfin[bb][o] = vf;
            if (it == NITER - 1)
                out[((size_t)(b0 + bb) * C_ + c) * O_ + o] = vf;
        }

        // 3) agreement update (skip on last iteration)
        if (it != NITER - 1) {
            __syncthreads();
            const float4 v0 = *(const float4*)&vfin[0][oq * 4];
            const float4 v1 = *(const float4*)&vfin[1][oq * 4];
            #pragma unroll
            for (int k = 0; k < KPT; ++k) {
                const int r = k * RPP + rl;
                const float4 uv = *(const float4*)&u1s[r][oq * 4];
                float d0 = u0[k][0] * v0.x + u0[k][1] * v0.y +
                           u0[k][2] * v0.z + u0[k][3] * v0.w;
                float d1 = uv.x * v1.x + uv.y * v1.y +
                           uv.z * v1.z + uv.w * v1.w;
                d0 += __shfl_xor(d0, 1);
                d0 += __shfl_xor(d0, 2);
                d1 += __shfl_xor(d1, 1);
                d1 += __shfl_xor(d1, 2);
                lg0[k] += d0;
                lg1[k] += d1;
            }
        }
    }
}

extern "C" void kernel_launch(void* const* d_in, const int* in_sizes, int n_in,
                              void* d_out, int out_size, void* d_ws, size_t ws_size,
                              hipStream_t stream) {
    const float* x = (const float*)d_in[0];
    const float* w = (const float*)d_in[1];
    float* out = (float*)d_out;
    capsule_routing_kernel<<<dim3(C_ * (B_ / BPB)), dim3(T_), 0, stream>>>(x, w, out);
}